// Round 1
// baseline (1418.307 us; speedup 1.0000x reference)
//
#include <hip/hip_runtime.h>
#include <hip/hip_bf16.h>
#include <math.h>

#define B_ 16
#define C_ 2048
#define HW_ 4096
#define NPIX_ 65536
#define PD_ 128
#define AD_ 64
#define S_ 64
#define BN_EPS_ 1e-5f
#define TEMP_ 0.1f
#define BTEMP_ 0.07f
#define THR_ 0.7f
#define LW_ 0.1f

// ---------------- zero init ----------------
__global__ void zero_kernel(float* ssq, float* out) {
    int g = blockIdx.x * blockDim.x + threadIdx.x;
    if (g < PD_) ssq[g] = 0.0f;
    if (g == 0) out[0] = 0.0f;
}

// ---------------- transpose weights ----------------
// W1t[k*128+c] = W1[c*2048+k]; Wa1t[k*64+j] = Wa1[j*2048+k]; W2t[k*128+o] = W2[o*128+k]
__global__ void prep_kernel(const float* __restrict__ W1, const float* __restrict__ Wa1,
                            const float* __restrict__ W2, float* __restrict__ W1t,
                            float* __restrict__ Wa1t, float* __restrict__ W2t) {
    int g = blockIdx.x * blockDim.x + threadIdx.x;
    if (g < C_ * PD_) { int k = g >> 7, c = g & 127; W1t[g] = W1[c * C_ + k]; }
    if (g < C_ * AD_) { int k = g >> 6, j = g & 63;  Wa1t[g] = Wa1[j * C_ + k]; }
    if (g < PD_ * PD_){ int k = g >> 7, c = g & 127; W2t[g] = W2[c * PD_ + k]; }
}

// ---------------- per-channel sum of feats over (B,H,W) ----------------
__global__ __launch_bounds__(256) void colsum_kernel(const float* __restrict__ feats,
                                                     float* __restrict__ xsum) {
    int c = blockIdx.x, t = threadIdx.x;
    float acc = 0.0f;
    for (int b = 0; b < B_; b++) {
        const float4* p4 = (const float4*)(feats + (size_t)b * C_ * HW_ + (size_t)c * HW_);
        for (int i = t; i < HW_ / 4; i += 256) {
            float4 v = p4[i];
            acc += v.x + v.y + v.z + v.w;
        }
    }
    for (int o = 32; o > 0; o >>= 1) acc += __shfl_down(acc, o, 64);
    __shared__ float red[4];
    if ((t & 63) == 0) red[t >> 6] = acc;
    __syncthreads();
    if (t == 0) xsum[c] = red[0] + red[1] + red[2] + red[3];
}

// ---------------- fused GEMM + square-reduce: ssq[c] = sum_p (w1_c . x_p)^2 ----------------
// tiles: 64 pixels x 128 channels per block, K-chunks of 32
#define TP_ 64
#define KC_ 32
__global__ __launch_bounds__(256) void hsq_kernel(const float* __restrict__ feats,
                                                  const float* __restrict__ W1t,
                                                  float* __restrict__ ssq) {
    __shared__ float xs[KC_][TP_];     // 8 KB
    __shared__ float ws[KC_][PD_];     // 16 KB
    __shared__ float red2[8 * PD_];    // 4 KB
    int tile = blockIdx.x;                  // 0..1023
    int b = tile >> 6;
    int hw0 = (tile & 63) << 6;
    int t = threadIdx.x;
    int cg = (t & 31) * 4;                  // channel group base
    int pg = (t >> 5) * 8;                  // pixel group base
    const float* fb = feats + (size_t)b * C_ * HW_ + hw0;

    float acc[4][8];
#pragma unroll
    for (int a = 0; a < 4; a++)
#pragma unroll
        for (int p = 0; p < 8; p++) acc[a][p] = 0.0f;

    for (int k0 = 0; k0 < C_; k0 += KC_) {
#pragma unroll
        for (int i = 0; i < 8; i++) {               // stage 32x64 x-chunk
            int j = t + 256 * i;
            int kk = j >> 6, pp = j & 63;
            xs[kk][pp] = fb[(size_t)(k0 + kk) * HW_ + pp];
        }
#pragma unroll
        for (int i = 0; i < 16; i++) {              // stage 32x128 w-chunk
            int j = t + 256 * i;
            int kk = j >> 7, cc = j & 127;
            ws[kk][cc] = W1t[(k0 + kk) * PD_ + cc];
        }
        __syncthreads();
#pragma unroll
        for (int k = 0; k < KC_; k++) {
            float4 w4 = *(const float4*)&ws[k][cg];
            float4 xa = *(const float4*)&xs[k][pg];
            float4 xb = *(const float4*)&xs[k][pg + 4];
            float wv[4] = {w4.x, w4.y, w4.z, w4.w};
            float xv[8] = {xa.x, xa.y, xa.z, xa.w, xb.x, xb.y, xb.z, xb.w};
#pragma unroll
            for (int a = 0; a < 4; a++)
#pragma unroll
                for (int p = 0; p < 8; p++) acc[a][p] = fmaf(wv[a], xv[p], acc[a][p]);
        }
        __syncthreads();
    }
    // square + reduce over this block's 64 pixels
#pragma unroll
    for (int a = 0; a < 4; a++) {
        float cs = 0.0f;
#pragma unroll
        for (int p = 0; p < 8; p++) cs = fmaf(acc[a][p], acc[a][p], cs);
        red2[(t >> 5) * PD_ + cg + a] = cs;
    }
    __syncthreads();
    if (t < PD_) {
        float tot = 0.0f;
#pragma unroll
        for (int g = 0; g < 8; g++) tot += red2[g * PD_ + t];
        atomicAdd(&ssq[t], tot);
    }
}

// ---------------- finalize BN stats ----------------
__global__ void stats_kernel(const float* __restrict__ xsum, const float* __restrict__ ssq,
                             const float* __restrict__ W1t, const float* __restrict__ b1,
                             float* __restrict__ mean, float* __restrict__ invstd) {
    int c = threadIdx.x;  // 0..127
    float m0 = 0.0f;
    for (int k = 0; k < C_; k++) m0 = fmaf(W1t[k * PD_ + c], xsum[k], m0);
    m0 *= (1.0f / NPIX_);
    float var = ssq[c] * (1.0f / NPIX_) - m0 * m0;
    mean[c] = m0 + b1[c];
    invstd[c] = rsqrtf(var + BN_EPS_);
}

// ---------------- first 64 valid pixels per image (row-major order) ----------------
__global__ __launch_bounds__(256) void find_kernel(const int* __restrict__ labels,
                                                   int* __restrict__ idx) {
    __shared__ int cnt[256];
    __shared__ int pref[257];
    int b = blockIdx.x, t = threadIdx.x;
    const int* lb = labels + b * HW_;
    int base = t * 16, c0 = 0;
    for (int i = 0; i < 16; i++) c0 += (lb[base + i] == 1);
    cnt[t] = c0;
    __syncthreads();
    if (t == 0) {
        int s = 0;
        for (int i = 0; i < 256; i++) { pref[i] = s; s += cnt[i]; }
        pref[256] = s;
    }
    __syncthreads();
    int r = pref[t];
    for (int i = 0; i < 16; i++) {
        if (lb[base + i] == 1) {
            if (r < S_) idx[b * S_ + r] = base + i;
            r++;
        }
    }
    if (t == 0) {
        for (int k = pref[256]; k < S_; k++) idx[b * S_ + k] = 0;  // fill_value=0
    }
}

// ---------------- per-sample forward: proj (post BN/ReLU/W2) + attention weight ----------------
__global__ __launch_bounds__(256) void sample_kernel(
        const float* __restrict__ feats, const float* __restrict__ W1t,
        const float* __restrict__ b1, const float* __restrict__ mean,
        const float* __restrict__ invstd, const float* __restrict__ gamma,
        const float* __restrict__ beta, const float* __restrict__ W2t,
        const float* __restrict__ b2, const float* __restrict__ Wa1t,
        const float* __restrict__ ba1, const float* __restrict__ Wa2,
        const float* __restrict__ ba2, const int* __restrict__ idx,
        float* __restrict__ projs, float* __restrict__ tw) {
    __shared__ float x[C_];    // 8 KB
    __shared__ float rh[PD_];
    __shared__ float av[AD_];
    int s = blockIdx.x;
    int b = s >> 6;
    int pix = idx[s];
    int t = threadIdx.x;
    const float* fb = feats + (size_t)b * C_ * HW_ + pix;
    for (int c = t; c < C_; c += 256) x[c] = fb[(size_t)c * HW_];
    __syncthreads();
    if (t < PD_) {
        float h = b1[t];
        for (int k = 0; k < C_; k++) h = fmaf(W1t[k * PD_ + t], x[k], h);
        float r = (h - mean[t]) * invstd[t] * gamma[t] + beta[t];
        rh[t] = r > 0.0f ? r : 0.0f;
    } else if (t < PD_ + AD_) {
        int j = t - PD_;
        float a = ba1[j];
        for (int k = 0; k < C_; k++) a = fmaf(Wa1t[k * AD_ + j], x[k], a);
        av[j] = a > 0.0f ? a : 0.0f;
    }
    __syncthreads();
    if (t < PD_) {
        float p = b2[t];
        for (int j = 0; j < PD_; j++) p = fmaf(W2t[j * PD_ + t], rh[j], p);
        projs[s * PD_ + t] = p;
    } else if (t == PD_) {
        float a2 = ba2[0];
        for (int j = 0; j < AD_; j++) a2 = fmaf(Wa2[j], av[j], a2);
        tw[s] = 1.0f / (1.0f + expf(-a2));
    }
}

// ---------------- per-image contrastive loss ----------------
__global__ __launch_bounds__(256) void loss_kernel(const float* __restrict__ projs,
                                                   const float* __restrict__ tw,
                                                   float* __restrict__ out) {
    __shared__ float f[S_][PD_ + 1];   // padded: 33 KB
    __shared__ float w[S_], inv[S_], rowsum[S_];
    __shared__ float sims[S_ * S_];    // 16 KB
    __shared__ float red[4];
    int b = blockIdx.x, t = threadIdx.x;
    for (int e = t; e < S_ * PD_; e += 256) {
        int i = e >> 7, c = e & 127;
        f[i][c] = projs[(b * S_ + i) * PD_ + c];
    }
    if (t < S_) w[t] = tw[b * S_ + t];
    __syncthreads();
    if (t < S_) {
        float s2 = 0.0f;
        for (int c = 0; c < PD_; c++) { float v = f[t][c]; s2 = fmaf(v, v, s2); }
        float n = sqrtf(s2);
        n = n < 1e-12f ? 1e-12f : n;
        inv[t] = 1.0f / n;
    }
    __syncthreads();
    for (int e = t; e < S_ * PD_; e += 256) {
        int i = e >> 7, c = e & 127;
        f[i][c] *= inv[i];
    }
    __syncthreads();
#pragma unroll
    for (int r = 0; r < 16; r++) {
        int e = t + 256 * r;
        int i = e >> 6, j = e & 63;
        float d = 0.0f;
        for (int c = 0; c < PD_; c++) d = fmaf(f[i][c], f[j][c], d);
        sims[e] = d * (1.0f / TEMP_);
    }
    __syncthreads();
    if (t < S_) {
        float rs = 0.0f;
        for (int jj = 0; jj < S_; jj++) {
            int j = (jj + t) & 63;                 // stagger: avoid bank conflicts
            rs += expf(sims[t * S_ + j]);
        }
        rowsum[t] = rs;
    }
    __syncthreads();
    float acc = 0.0f;
#pragma unroll
    for (int r = 0; r < 16; r++) {
        int e = t + 256 * r;
        int i = e >> 6, j = e & 63;
        float sv = sims[e];
        if (sv > THR_ && i != j) {
            float lp = logf(expf(sv) / rowsum[i] + 1e-10f);
            acc += w[i] * w[j] * lp;
        }
    }
    for (int o = 32; o > 0; o >>= 1) acc += __shfl_down(acc, o, 64);
    if ((t & 63) == 0) red[t >> 6] = acc;
    __syncthreads();
    if (t == 0) {
        float total = red[0] + red[1] + red[2] + red[3];
        float twsum = 0.0f;
        for (int i = 0; i < S_; i++) twsum += w[i];
        float loss = -(TEMP_ / BTEMP_) * total / twsum;
        atomicAdd(out, loss * (LW_ / B_));
    }
}

extern "C" void kernel_launch(void* const* d_in, const int* in_sizes, int n_in,
                              void* d_out, int out_size, void* d_ws, size_t ws_size,
                              hipStream_t stream) {
    const float* feats = (const float*)d_in[0];
    const int*   labels = (const int*)d_in[1];
    const float* W1 = (const float*)d_in[2];
    const float* b1 = (const float*)d_in[3];
    const float* gamma = (const float*)d_in[4];
    const float* beta = (const float*)d_in[5];
    const float* W2 = (const float*)d_in[6];
    const float* b2 = (const float*)d_in[7];
    const float* Wa1 = (const float*)d_in[8];
    const float* ba1 = (const float*)d_in[9];
    const float* Wa2 = (const float*)d_in[10];
    const float* ba2 = (const float*)d_in[11];
    float* out = (float*)d_out;

    // workspace layout (floats)
    float* ws = (float*)d_ws;
    float* xsum   = ws;                       // 2048
    float* ssq    = xsum + C_;                // 128
    float* mean   = ssq + PD_;                // 128
    float* invstd = mean + PD_;               // 128
    float* tw     = invstd + PD_;             // 1024
    int*   idx    = (int*)(tw + B_ * S_);     // 1024 ints
    float* projs  = (float*)(idx + B_ * S_);  // 131072
    float* W1t    = projs + B_ * S_ * PD_;    // 262144
    float* Wa1t   = W1t + C_ * PD_;           // 131072
    float* W2t    = Wa1t + C_ * AD_;          // 16384

    zero_kernel<<<1, 256, 0, stream>>>(ssq, out);
    prep_kernel<<<(C_ * PD_) / 256, 256, 0, stream>>>(W1, Wa1, W2, W1t, Wa1t, W2t);
    colsum_kernel<<<C_, 256, 0, stream>>>(feats, xsum);
    hsq_kernel<<<NPIX_ / TP_, 256, 0, stream>>>(feats, W1t, ssq);
    stats_kernel<<<1, PD_, 0, stream>>>(xsum, ssq, W1t, b1, mean, invstd);
    find_kernel<<<B_, 256, 0, stream>>>(labels, idx);
    sample_kernel<<<B_ * S_, 256, 0, stream>>>(feats, W1t, b1, mean, invstd, gamma, beta,
                                               W2t, b2, Wa1t, ba1, Wa2, ba2, idx, projs, tw);
    loss_kernel<<<B_, 256, 0, stream>>>(projs, tw, out);
}

// Round 2
// 965.590 us; speedup vs baseline: 1.4689x; 1.4689x over previous
//
#include <hip/hip_runtime.h>
#include <hip/hip_bf16.h>
#include <math.h>

#define B_ 16
#define C_ 2048
#define HW_ 4096
#define NPIX_ 65536
#define PD_ 128
#define AD_ 64
#define S_ 64
#define BN_EPS_ 1e-5f
#define TEMP_ 0.1f
#define BTEMP_ 0.07f
#define THR_ 0.7f
#define LW_ 0.1f

typedef __attribute__((ext_vector_type(8))) short short8;
typedef __attribute__((ext_vector_type(4))) float floatx4;

__device__ __forceinline__ unsigned short f2bf(float x) {
    unsigned int u = __float_as_uint(x);
    u += 0x7fffu + ((u >> 16) & 1u);   // round-to-nearest-even
    return (unsigned short)(u >> 16);
}

// ---------------- zero init ----------------
__global__ void zero_kernel(float* xsum, float* ssq, float* out) {
    int t = threadIdx.x;
    for (int i = t; i < C_; i += 256) xsum[i] = 0.0f;
    if (t < PD_) ssq[t] = 0.0f;
    if (t == 0) out[0] = 0.0f;
}

// ---------------- transpose weights + pack W1 into bf16 MFMA B-fragment order ----------------
// W1t[k*128+c] = W1[c*2048+k]; Wa1t[k*64+j] = Wa1[j*2048+k]; W2t[k*128+o] = W2[o*128+k]
// Bpk unit u = ((kc*4 + q)*128 + c): 8 bf16 = W1[c][kc*32+q*8 .. +7]  (16B per unit)
__global__ void prep_kernel(const float* __restrict__ W1, const float* __restrict__ Wa1,
                            const float* __restrict__ W2, float* __restrict__ W1t,
                            float* __restrict__ Wa1t, float* __restrict__ W2t,
                            uint4* __restrict__ Bpk) {
    int g = blockIdx.x * blockDim.x + threadIdx.x;
    if (g < C_ * PD_) { int k = g >> 7, c = g & 127; W1t[g] = W1[c * C_ + k]; }
    if (g < C_ * AD_) { int k = g >> 6, j = g & 63;  Wa1t[g] = Wa1[j * C_ + k]; }
    if (g < PD_ * PD_){ int k = g >> 7, c = g & 127; W2t[g] = W2[c * PD_ + k]; }
    if (g < 64 * 4 * PD_) {            // 32768 units
        int kc = g >> 9, q = (g >> 7) & 3, c = g & 127;
        const float* src = W1 + (size_t)c * C_ + kc * 32 + q * 8;
        unsigned int w[4];
#pragma unroll
        for (int h = 0; h < 4; h++) {
            unsigned int lo = f2bf(src[2 * h]);
            unsigned int hi = f2bf(src[2 * h + 1]);
            w[h] = lo | (hi << 16);
        }
        Bpk[g] = make_uint4(w[0], w[1], w[2], w[3]);
    }
}

// ---------------- fused: feats column-sum + sum_p (W1 . x_p)^2 via bf16 MFMA ----------------
// grid: 1024 blocks = 16 images x 64 pixel-tiles (64 px). 256 thr = 4 waves, each wave owns 16 px.
#define NKC_ 64   // 2048 / 32
__global__ __launch_bounds__(256) void fused_stats_kernel(const float* __restrict__ feats,
                                                          const uint4* __restrict__ Bpk,
                                                          float* __restrict__ xsum,
                                                          float* __restrict__ ssq) {
    __shared__ uint4 bw[2][512];       // 2 x 8KB: B frags for one K-chunk of 32
    __shared__ float lxsum[C_];        // 8KB per-block column sums
    __shared__ float red[4][PD_];      // 2KB cross-wave ssq reduce

    int t = threadIdx.x;
    for (int i = t; i < C_; i += 256) lxsum[i] = 0.0f;

    int tile = blockIdx.x;
    int b = tile >> 6;
    int hw0 = (tile & 63) << 6;
    int wave = t >> 6, lane = t & 63;
    int qd = lane >> 4, ln16 = lane & 15;
    const float* fb = feats + (size_t)b * C_ * HW_ + (hw0 + wave * 16 + ln16);

    floatx4 acc[8];
#pragma unroll
    for (int nt = 0; nt < 8; nt++) acc[nt] = (floatx4)0.0f;

    // prologue: stage chunk 0
    bw[0][t] = Bpk[t];
    bw[0][t + 256] = Bpk[t + 256];
    __syncthreads();

    for (int kc = 0; kc < NKC_; kc++) {
        int cur = kc & 1;
        uint4 u0, u1;
        if (kc + 1 < NKC_) {                       // prefetch next B chunk
            u0 = Bpk[(kc + 1) * 512 + t];
            u1 = Bpk[(kc + 1) * 512 + t + 256];
        }
        // A: 8 scalar global loads (pixel fixed, k = kc*32 + qd*8 + j)
        const float* pk = fb + (size_t)(kc * 32 + qd * 8) * HW_;
        float av[8];
#pragma unroll
        for (int j = 0; j < 8; j++) av[j] = pk[(size_t)j * HW_];

        // column-sum: reduce over the 16 pixels in this quarter-wave
#pragma unroll
        for (int j = 0; j < 8; j++) {
            float v = av[j];
            v += __shfl_xor(v, 1, 64);
            v += __shfl_xor(v, 2, 64);
            v += __shfl_xor(v, 4, 64);
            v += __shfl_xor(v, 8, 64);
            if (ln16 == 0) atomicAdd(&lxsum[kc * 32 + qd * 8 + j], v);
        }

        // convert to bf16 A-fragment
        short8 afrag;
#pragma unroll
        for (int j = 0; j < 8; j++) afrag[j] = (short)f2bf(av[j]);

        // 8 MFMAs over the 128 output channels
#pragma unroll
        for (int nt = 0; nt < 8; nt++) {
            short8 bfrag = *reinterpret_cast<const short8*>(&bw[cur][qd * 128 + nt * 16 + ln16]);
            acc[nt] = __builtin_amdgcn_mfma_f32_16x16x32_bf16(afrag, bfrag, acc[nt], 0, 0, 0);
        }

        if (kc + 1 < NKC_) {
            bw[cur ^ 1][t] = u0;
            bw[cur ^ 1][t + 256] = u1;
        }
        __syncthreads();
    }

    // ssq epilogue: square-accumulate over this wave's 16 pixels, then cross-wave
#pragma unroll
    for (int nt = 0; nt < 8; nt++) {
        float s = 0.0f;
#pragma unroll
        for (int r = 0; r < 4; r++) s = fmaf(acc[nt][r], acc[nt][r], s);
        s += __shfl_xor(s, 16, 64);
        s += __shfl_xor(s, 32, 64);
        if (qd == 0) red[wave][nt * 16 + ln16] = s;
    }
    __syncthreads();
    if (t < PD_) {
        float tot = red[0][t] + red[1][t] + red[2][t] + red[3][t];
        atomicAdd(&ssq[t], tot);
    }
    for (int i = t; i < C_; i += 256) atomicAdd(&xsum[i], lxsum[i]);
}

// ---------------- finalize BN stats (parallel over channels) ----------------
__global__ __launch_bounds__(256) void stats_kernel(const float* __restrict__ W1,
                                                    const float* __restrict__ xsum,
                                                    const float* __restrict__ ssq,
                                                    const float* __restrict__ b1,
                                                    float* __restrict__ mean,
                                                    float* __restrict__ invstd) {
    int c = blockIdx.x, t = threadIdx.x;
    const float* row = W1 + (size_t)c * C_;
    float acc = 0.0f;
    for (int k = t; k < C_; k += 256) acc = fmaf(row[k], xsum[k], acc);
    for (int o = 32; o > 0; o >>= 1) acc += __shfl_down(acc, o, 64);
    __shared__ float red[4];
    if ((t & 63) == 0) red[t >> 6] = acc;
    __syncthreads();
    if (t == 0) {
        float m0 = (red[0] + red[1] + red[2] + red[3]) * (1.0f / NPIX_);
        float var = ssq[c] * (1.0f / NPIX_) - m0 * m0;
        mean[c] = m0 + b1[c];
        invstd[c] = rsqrtf(var + BN_EPS_);
    }
}

// ---------------- first 64 valid pixels per image (row-major order) ----------------
__global__ __launch_bounds__(256) void find_kernel(const int* __restrict__ labels,
                                                   int* __restrict__ idx) {
    __shared__ int cnt[256];
    __shared__ int pref[257];
    int b = blockIdx.x, t = threadIdx.x;
    const int* lb = labels + b * HW_;
    int base = t * 16, c0 = 0;
    for (int i = 0; i < 16; i++) c0 += (lb[base + i] == 1);
    cnt[t] = c0;
    __syncthreads();
    if (t == 0) {
        int s = 0;
        for (int i = 0; i < 256; i++) { pref[i] = s; s += cnt[i]; }
        pref[256] = s;
    }
    __syncthreads();
    int r = pref[t];
    for (int i = 0; i < 16; i++) {
        if (lb[base + i] == 1) {
            if (r < S_) idx[b * S_ + r] = base + i;
            r++;
        }
    }
    if (t == 0) {
        for (int k = pref[256]; k < S_; k++) idx[b * S_ + k] = 0;  // fill_value=0
    }
}

// ---------------- per-sample forward: proj (post BN/ReLU/W2) + attention weight ----------------
__global__ __launch_bounds__(256) void sample_kernel(
        const float* __restrict__ feats, const float* __restrict__ W1t,
        const float* __restrict__ b1, const float* __restrict__ mean,
        const float* __restrict__ invstd, const float* __restrict__ gamma,
        const float* __restrict__ beta, const float* __restrict__ W2t,
        const float* __restrict__ b2, const float* __restrict__ Wa1t,
        const float* __restrict__ ba1, const float* __restrict__ Wa2,
        const float* __restrict__ ba2, const int* __restrict__ idx,
        float* __restrict__ projs, float* __restrict__ tw) {
    __shared__ float x[C_];    // 8 KB
    __shared__ float rh[PD_];
    __shared__ float av[AD_];
    int s = blockIdx.x;
    int b = s >> 6;
    int pix = idx[s];
    int t = threadIdx.x;
    const float* fb = feats + (size_t)b * C_ * HW_ + pix;
    for (int c = t; c < C_; c += 256) x[c] = fb[(size_t)c * HW_];
    __syncthreads();
    if (t < PD_) {
        float h = b1[t];
        for (int k = 0; k < C_; k++) h = fmaf(W1t[k * PD_ + t], x[k], h);
        float r = (h - mean[t]) * invstd[t] * gamma[t] + beta[t];
        rh[t] = r > 0.0f ? r : 0.0f;
    } else if (t < PD_ + AD_) {
        int j = t - PD_;
        float a = ba1[j];
        for (int k = 0; k < C_; k++) a = fmaf(Wa1t[k * AD_ + j], x[k], a);
        av[j] = a > 0.0f ? a : 0.0f;
    }
    __syncthreads();
    if (t < PD_) {
        float p = b2[t];
        for (int j = 0; j < PD_; j++) p = fmaf(W2t[j * PD_ + t], rh[j], p);
        projs[s * PD_ + t] = p;
    } else if (t == PD_) {
        float a2 = ba2[0];
        for (int j = 0; j < AD_; j++) a2 = fmaf(Wa2[j], av[j], a2);
        tw[s] = 1.0f / (1.0f + expf(-a2));
    }
}

// ---------------- per-image contrastive loss ----------------
__global__ __launch_bounds__(256) void loss_kernel(const float* __restrict__ projs,
                                                   const float* __restrict__ tw,
                                                   float* __restrict__ out) {
    __shared__ float f[S_][PD_ + 1];   // padded
    __shared__ float w[S_], inv[S_], rowsum[S_];
    __shared__ float sims[S_ * S_];    // 16 KB
    __shared__ float red[4];
    int b = blockIdx.x, t = threadIdx.x;
    for (int e = t; e < S_ * PD_; e += 256) {
        int i = e >> 7, c = e & 127;
        f[i][c] = projs[(b * S_ + i) * PD_ + c];
    }
    if (t < S_) w[t] = tw[b * S_ + t];
    __syncthreads();
    if (t < S_) {
        float s2 = 0.0f;
        for (int c = 0; c < PD_; c++) { float v = f[t][c]; s2 = fmaf(v, v, s2); }
        float n = sqrtf(s2);
        n = n < 1e-12f ? 1e-12f : n;
        inv[t] = 1.0f / n;
    }
    __syncthreads();
    for (int e = t; e < S_ * PD_; e += 256) {
        int i = e >> 7, c = e & 127;
        f[i][c] *= inv[i];
    }
    __syncthreads();
#pragma unroll
    for (int r = 0; r < 16; r++) {
        int e = t + 256 * r;
        int i = e >> 6, j = e & 63;
        float d = 0.0f;
        for (int c = 0; c < PD_; c++) d = fmaf(f[i][c], f[j][c], d);
        sims[e] = d * (1.0f / TEMP_);
    }
    __syncthreads();
    if (t < S_) {
        float rs = 0.0f;
        for (int jj = 0; jj < S_; jj++) {
            int j = (jj + t) & 63;
            rs += expf(sims[t * S_ + j]);
        }
        rowsum[t] = rs;
    }
    __syncthreads();
    float acc = 0.0f;
#pragma unroll
    for (int r = 0; r < 16; r++) {
        int e = t + 256 * r;
        int i = e >> 6, j = e & 63;
        float sv = sims[e];
        if (sv > THR_ && i != j) {
            float lp = logf(expf(sv) / rowsum[i] + 1e-10f);
            acc += w[i] * w[j] * lp;
        }
    }
    for (int o = 32; o > 0; o >>= 1) acc += __shfl_down(acc, o, 64);
    if ((t & 63) == 0) red[t >> 6] = acc;
    __syncthreads();
    if (t == 0) {
        float total = red[0] + red[1] + red[2] + red[3];
        float twsum = 0.0f;
        for (int i = 0; i < S_; i++) twsum += w[i];
        float loss = -(TEMP_ / BTEMP_) * total / twsum;
        atomicAdd(out, loss * (LW_ / B_));
    }
}

extern "C" void kernel_launch(void* const* d_in, const int* in_sizes, int n_in,
                              void* d_out, int out_size, void* d_ws, size_t ws_size,
                              hipStream_t stream) {
    const float* feats = (const float*)d_in[0];
    const int*   labels = (const int*)d_in[1];
    const float* W1 = (const float*)d_in[2];
    const float* b1 = (const float*)d_in[3];
    const float* gamma = (const float*)d_in[4];
    const float* beta = (const float*)d_in[5];
    const float* W2 = (const float*)d_in[6];
    const float* b2 = (const float*)d_in[7];
    const float* Wa1 = (const float*)d_in[8];
    const float* ba1 = (const float*)d_in[9];
    const float* Wa2 = (const float*)d_in[10];
    const float* ba2 = (const float*)d_in[11];
    float* out = (float*)d_out;

    // workspace layout (floats)
    float* ws = (float*)d_ws;
    float* xsum   = ws;                       // 2048
    float* ssq    = xsum + C_;                // 128
    float* mean   = ssq + PD_;                // 128
    float* invstd = mean + PD_;               // 128
    float* tw     = invstd + PD_;             // 1024
    int*   idx    = (int*)(tw + B_ * S_);     // 1024 ints
    float* projs  = (float*)(idx + B_ * S_);  // 131072
    float* W1t    = projs + B_ * S_ * PD_;    // 262144
    float* Wa1t   = W1t + C_ * PD_;           // 131072
    float* W2t    = Wa1t + C_ * AD_;          // 16384
    // align Bpk to 16B (offset so far is a multiple of 16 floats anyway)
    uint4* Bpk    = (uint4*)(W2t + PD_ * PD_);// 32768 uint4 = 512 KB

    zero_kernel<<<1, 256, 0, stream>>>(xsum, ssq, out);
    prep_kernel<<<(C_ * PD_) / 256, 256, 0, stream>>>(W1, Wa1, W2, W1t, Wa1t, W2t, Bpk);
    fused_stats_kernel<<<1024, 256, 0, stream>>>(feats, Bpk, xsum, ssq);
    stats_kernel<<<PD_, 256, 0, stream>>>(W1, xsum, ssq, b1, mean, invstd);
    find_kernel<<<B_, 256, 0, stream>>>(labels, idx);
    sample_kernel<<<B_ * S_, 256, 0, stream>>>(feats, W1t, b1, mean, invstd, gamma, beta,
                                               W2t, b2, Wa1t, ba1, Wa2, ba2, idx, projs, tw);
    loss_kernel<<<B_, 256, 0, stream>>>(projs, tw, out);
}